// Round 6
// baseline (134.504 us; speedup 1.0000x reference)
//
#include <hip/hip_runtime.h>

// VQ nearest-neighbor via f16-split MFMA. N=65536 queries, DIM=64, K=1024.
// v = dot(z,c) - csq[k]/2; argmax_k v == argmin_k ||z-c||^2.
// 2-term f16 split (rounds 4-5, absmax=0): dot ~= zh.ch + 2^-11(zh.cl'+zl'.ch).
//
// Round 6: occupancy fix. R5 ran 2048 waves (2/SIMD) and sat latency-bound on
// L2 B-fetches (vq ~30 us vs 7.8 us L2-pipe floor). Now K-split x4: block =
// 4 waves = 1 query-group(64q) x 4 K-quarters(256 codes) -> 4096 waves =
// 4 waves/SIMD (launch_bounds(256,4) pins VGPR <= 128). B-traffic unchanged.
// prep widened 4 -> 64 blocks (4 dims/thread, shfl csq reduction).

typedef _Float16 half8 __attribute__((ext_vector_type(8)));
typedef _Float16 half4v __attribute__((ext_vector_type(4)));
typedef float float4v __attribute__((ext_vector_type(4)));

constexpr int KCODES = 1024;
constexpr int DIM = 64;
constexpr int BLOCK = 256;

// d_ws layout
constexpr size_t WS_CSQN = 0;      // 1024 f32 (-csq/2)             = 4 KB
constexpr size_t WS_CBF = 4096;    // fragment-ordered split cb f16 = 256 KB

// Fragment-ordered split codebook:
// cbf[((T)*2+hl)*512 + fraglane*8 + j8], T = (k>>4)*2 + kt, fraglane =
// quad*16 + (k&15), dim = kt*32 + quad*8 + j8. hl=0: f16 high; hl=1: res*2^11.
// Fine-grained prep: 64 blocks x 256 thr; thread = (code c_local = tid>>4,
// chunk = tid&15 -> dims 4*chunk..+3). Threads sharing a code are a 16-lane
// group within one wave -> shfl_xor csq reduction.
__global__ __launch_bounds__(BLOCK) void prep_kernel(
    const float* __restrict__ cb, _Float16* __restrict__ cbf,
    float* __restrict__ csqn) {
  const int tid = threadIdx.x;
  const int chunk = tid & 15;
  const int k = blockIdx.x * 16 + (tid >> 4);
  const float4 v = ((const float4*)(cb + (size_t)k * DIM))[chunk];

  float s = fmaf(v.x, v.x, fmaf(v.y, v.y, fmaf(v.z, v.z, v.w * v.w)));
#pragma unroll
  for (int sft = 1; sft < 16; sft <<= 1) s += __shfl_xor(s, sft);
  if (chunk == 0) csqn[k] = -0.5f * s;

  half4v h4, l4;
  const float x[4] = {v.x, v.y, v.z, v.w};
#pragma unroll
  for (int j = 0; j < 4; ++j) {
    const _Float16 h = (_Float16)x[j];
    h4[j] = h;
    l4[j] = (_Float16)((x[j] - (float)h) * 2048.0f);
  }
  const int d0 = chunk * 4;                    // first dim of this chunk
  const int kt = d0 >> 5;
  const int quad = (d0 >> 3) & 3;
  const int j8 = d0 & 7;                       // 0 or 4
  const int fraglane = quad * 16 + (k & 15);
  const size_t T = (size_t)(k >> 4) * 2 + kt;
  *(half4v*)(cbf + (T * 2 + 0) * 512 + fraglane * 8 + j8) = h4;
  *(half4v*)(cbf + (T * 2 + 1) * 512 + fraglane * 8 + j8) = l4;
}

// Block = 256 thr = 4 waves; wave kh handles codes [kh*256, kh*256+256) for
// the block's 64 queries. A-fragments resident all sweep; B = contiguous
// coalesced 1 KB global loads (L2-hot).
__global__ __launch_bounds__(BLOCK, 4) void vq_mfma(
    const float* __restrict__ z, const float4* __restrict__ cb4,
    const _Float16* __restrict__ cbf, const float* __restrict__ csqn_g,
    float4* __restrict__ out4) {
  __shared__ float scsqn[KCODES];
  __shared__ float rv[4][64];
  __shared__ int rk[4][64];
  __shared__ int sidx[64];

  const int tid = threadIdx.x;
  const int lane = tid & 63;
  const int kh = tid >> 6;     // K quarter
  const int m = lane & 15;
  const int quad = lane >> 4;

  ((float4*)scsqn)[tid] = ((const float4*)csqn_g)[tid];

  // A-fragments: 4 qtiles x 2 ktiles, h + l (64 VGPR). A[m][k=quad*8+j].
  const int qbase = blockIdx.x * 64;
  half8 ah[4][2], al[4][2];
#pragma unroll
  for (int qt = 0; qt < 4; ++qt) {
    const float* zr = z + (size_t)(qbase + qt * 16 + m) * DIM + quad * 8;
#pragma unroll
    for (int kt = 0; kt < 2; ++kt) {
      const float4 p0 = ((const float4*)(zr + kt * 32))[0];
      const float4 p1 = ((const float4*)(zr + kt * 32))[1];
      const float zf[8] = {p0.x, p0.y, p0.z, p0.w, p1.x, p1.y, p1.z, p1.w};
#pragma unroll
      for (int j = 0; j < 8; ++j) {
        const _Float16 h = (_Float16)zf[j];
        ah[qt][kt][j] = h;
        al[qt][kt][j] = (_Float16)((zf[j] - (float)h) * 2048.0f);
      }
    }
  }

  __syncthreads();  // scsqn visible

  const float4v zvec = {0.f, 0.f, 0.f, 0.f};
  float best[4][4];
  int bestk[4][4];
#pragma unroll
  for (int qt = 0; qt < 4; ++qt)
#pragma unroll
    for (int r = 0; r < 4; ++r) { best[qt][r] = -3.402823466e38f; bestk[qt][r] = 0; }

  // B base: this wave's K quarter (16 tiles x 2048 f16), fragment-ordered.
  const _Float16* bbase = cbf + (size_t)kh * 32768 + lane * 8;

#pragma unroll 2
  for (int t = 0; t < 16; ++t) {
    const _Float16* pt = bbase + (size_t)t * 2048;
    const half8 bh0 = *(const half8*)(pt);          // kt0, h
    const half8 bl0 = *(const half8*)(pt + 512);    // kt0, l
    const half8 bh1 = *(const half8*)(pt + 1024);   // kt1, h
    const half8 bl1 = *(const half8*)(pt + 1536);   // kt1, l

    const int k16 = kh * 256 + t * 16 + m;          // this lane's code column
    const float c = scsqn[k16];
    const float4v cvec = {c, c, c, c};

#pragma unroll
    for (int qt = 0; qt < 4; ++qt) {
      float4v am = __builtin_amdgcn_mfma_f32_16x16x32_f16(ah[qt][0], bh0, cvec, 0, 0, 0);
      am = __builtin_amdgcn_mfma_f32_16x16x32_f16(ah[qt][1], bh1, am, 0, 0, 0);
      float4v ax = __builtin_amdgcn_mfma_f32_16x16x32_f16(ah[qt][0], bl0, zvec, 0, 0, 0);
      ax = __builtin_amdgcn_mfma_f32_16x16x32_f16(ah[qt][1], bl1, ax, 0, 0, 0);
      ax = __builtin_amdgcn_mfma_f32_16x16x32_f16(al[qt][0], bh0, ax, 0, 0, 0);
      ax = __builtin_amdgcn_mfma_f32_16x16x32_f16(al[qt][1], bh1, ax, 0, 0, 0);
#pragma unroll
      for (int r = 0; r < 4; ++r) {
        const float v = fmaf(4.8828125e-4f, ax[r], am[r]);  // 2^-11
        // k ascending in t per lane: strict > keeps lowest-k maximum.
        if (v > best[qt][r]) { best[qt][r] = v; bestk[qt][r] = k16; }
      }
    }
  }

  // Cross-lane argmax over the 16 cols (m) in each quad; ties -> lower k.
#pragma unroll
  for (int qt = 0; qt < 4; ++qt)
#pragma unroll
    for (int r = 0; r < 4; ++r) {
      float b = best[qt][r];
      int bk = bestk[qt][r];
#pragma unroll
      for (int s = 1; s < 16; s <<= 1) {
        const float ob = __shfl_xor(b, s);
        const int obk = __shfl_xor(bk, s);
        if (ob > b || (ob == b && obk < bk)) { b = ob; bk = obk; }
      }
      if (m == 0) {
        const int qb = qt * 16 + quad * 4 + r;  // C row = quad*4 + r
        rv[kh][qb] = b;
        rk[kh][qb] = bk;
      }
    }
  __syncthreads();

  // Combine the 4 K-quarters in order (strict >: ties -> lower kh = lower k).
  if (tid < 64) {
    float b = rv[0][tid];
    int bk = rk[0][tid];
#pragma unroll
    for (int h = 1; h < 4; ++h) {
      const float d = rv[h][tid];
      if (d > b) { b = d; bk = rk[h][tid]; }
    }
    sidx[tid] = bk;
  }
  __syncthreads();

  // Gather winning fp32 codebook rows; coalesced float4 writes.
  const size_t obase = (size_t)blockIdx.x * 64 * (DIM / 4);
#pragma unroll
  for (int f0 = 0; f0 < 64 * (DIM / 4); f0 += BLOCK) {
    const int f = f0 + tid;
    const int q = f >> 4, e = f & 15;
    out4[obase + f] = cb4[(size_t)sidx[q] * (DIM / 4) + e];
  }
}

extern "C" void kernel_launch(void* const* d_in, const int* in_sizes, int n_in,
                              void* d_out, int out_size, void* d_ws, size_t ws_size,
                              hipStream_t stream) {
  const float* z = (const float*)d_in[0];
  const float* cb = (const float*)d_in[1];
  char* ws = (char*)d_ws;
  float* csqn = (float*)(ws + WS_CSQN);
  _Float16* cbf = (_Float16*)(ws + WS_CBF);

  const int nq = in_sizes[0] / DIM;  // 65536
  prep_kernel<<<KCODES / 16, BLOCK, 0, stream>>>(cb, cbf, csqn);
  vq_mfma<<<nq / 64, BLOCK, 0, stream>>>(z, (const float4*)cb, cbf, csqn,
                                         (float4*)d_out);
}

// Round 7
// 106.275 us; speedup vs baseline: 1.2656x; 1.2656x over previous
//
#include <hip/hip_runtime.h>

// VQ nearest-neighbor via f16-split MFMA. N=65536 queries, DIM=64, K=1024.
// v = dot(z,c) - csq[k]/2; argmax_k v == argmin_k ||z-c||^2.
// 2-term f16 split (rounds 4-6, absmax=0): dot ~= zh.ch + 2^-11(zh.cl'+zl'.ch).
//
// Round 7: R6 structure (K-split x4: block = 4 waves = 1 query-group(64q) x
// 4 K-quarters(256 codes), 4096 waves = 4/SIMD of work) but
// __launch_bounds__(256,3): R6's (256,4) capped VGPR at 128 < ~150 needed ->
// scratch spill (WRITE_SIZE 89 MB, vq 76 us). Cap 3/SIMD (~170 VGPR) holds
// A-fragments + argmin state resident; 3 waves/SIMD still beats R5's 2.

typedef _Float16 half8 __attribute__((ext_vector_type(8)));
typedef _Float16 half4v __attribute__((ext_vector_type(4)));
typedef float float4v __attribute__((ext_vector_type(4)));

constexpr int KCODES = 1024;
constexpr int DIM = 64;
constexpr int BLOCK = 256;

// d_ws layout
constexpr size_t WS_CSQN = 0;      // 1024 f32 (-csq/2)             = 4 KB
constexpr size_t WS_CBF = 4096;    // fragment-ordered split cb f16 = 256 KB

// Fragment-ordered split codebook:
// cbf[(T*2+hl)*512 + fraglane*8 + j8], T = (k>>4)*2 + kt, fraglane =
// quad*16 + (k&15), dim = kt*32 + quad*8 + j8. hl=0: f16 high; hl=1: res*2^11.
__global__ __launch_bounds__(BLOCK) void prep_kernel(
    const float* __restrict__ cb, _Float16* __restrict__ cbf,
    float* __restrict__ csqn) {
  const int tid = threadIdx.x;
  const int chunk = tid & 15;
  const int k = blockIdx.x * 16 + (tid >> 4);
  const float4 v = ((const float4*)(cb + (size_t)k * DIM))[chunk];

  float s = fmaf(v.x, v.x, fmaf(v.y, v.y, fmaf(v.z, v.z, v.w * v.w)));
#pragma unroll
  for (int sft = 1; sft < 16; sft <<= 1) s += __shfl_xor(s, sft);
  if (chunk == 0) csqn[k] = -0.5f * s;

  half4v h4, l4;
  const float x[4] = {v.x, v.y, v.z, v.w};
#pragma unroll
  for (int j = 0; j < 4; ++j) {
    const _Float16 h = (_Float16)x[j];
    h4[j] = h;
    l4[j] = (_Float16)((x[j] - (float)h) * 2048.0f);
  }
  const int d0 = chunk * 4;
  const int kt = d0 >> 5;
  const int quad = (d0 >> 3) & 3;
  const int j8 = d0 & 7;
  const int fraglane = quad * 16 + (k & 15);
  const size_t T = (size_t)(k >> 4) * 2 + kt;
  *(half4v*)(cbf + (T * 2 + 0) * 512 + fraglane * 8 + j8) = h4;
  *(half4v*)(cbf + (T * 2 + 1) * 512 + fraglane * 8 + j8) = l4;
}

// Block = 256 thr = 4 waves; wave kh handles codes [kh*256, kh*256+256) for
// the block's 64 queries. A-fragments resident all sweep; B = contiguous
// coalesced 1 KB global loads (L2-hot).
__global__ __launch_bounds__(BLOCK, 3) void vq_mfma(
    const float* __restrict__ z, const float4* __restrict__ cb4,
    const _Float16* __restrict__ cbf, const float* __restrict__ csqn_g,
    float4* __restrict__ out4) {
  __shared__ float scsqn[KCODES];
  __shared__ float rv[4][64];
  __shared__ int rk[4][64];
  __shared__ int sidx[64];

  const int tid = threadIdx.x;
  const int lane = tid & 63;
  const int kh = tid >> 6;     // K quarter
  const int m = lane & 15;
  const int quad = lane >> 4;

  ((float4*)scsqn)[tid] = ((const float4*)csqn_g)[tid];

  // A-fragments: 4 qtiles x 2 ktiles, h + l (64 VGPR). A[m][k=quad*8+j].
  const int qbase = blockIdx.x * 64;
  half8 ah[4][2], al[4][2];
#pragma unroll
  for (int qt = 0; qt < 4; ++qt) {
    const float* zr = z + (size_t)(qbase + qt * 16 + m) * DIM + quad * 8;
#pragma unroll
    for (int kt = 0; kt < 2; ++kt) {
      const float4 p0 = ((const float4*)(zr + kt * 32))[0];
      const float4 p1 = ((const float4*)(zr + kt * 32))[1];
      const float zf[8] = {p0.x, p0.y, p0.z, p0.w, p1.x, p1.y, p1.z, p1.w};
#pragma unroll
      for (int j = 0; j < 8; ++j) {
        const _Float16 h = (_Float16)zf[j];
        ah[qt][kt][j] = h;
        al[qt][kt][j] = (_Float16)((zf[j] - (float)h) * 2048.0f);
      }
    }
  }

  __syncthreads();  // scsqn visible

  const float4v zvec = {0.f, 0.f, 0.f, 0.f};
  float best[4][4];
  int bestk[4][4];
#pragma unroll
  for (int qt = 0; qt < 4; ++qt)
#pragma unroll
    for (int r = 0; r < 4; ++r) { best[qt][r] = -3.402823466e38f; bestk[qt][r] = 0; }

  // B base: this wave's K quarter (16 tiles x 2048 f16), fragment-ordered.
  const _Float16* bbase = cbf + (size_t)kh * 32768 + lane * 8;

#pragma unroll 2
  for (int t = 0; t < 16; ++t) {
    const _Float16* pt = bbase + (size_t)t * 2048;
    const half8 bh0 = *(const half8*)(pt);          // kt0, h
    const half8 bl0 = *(const half8*)(pt + 512);    // kt0, l
    const half8 bh1 = *(const half8*)(pt + 1024);   // kt1, h
    const half8 bl1 = *(const half8*)(pt + 1536);   // kt1, l

    const int k16 = kh * 256 + t * 16 + m;          // this lane's code column
    const float c = scsqn[k16];
    const float4v cvec = {c, c, c, c};

#pragma unroll
    for (int qt = 0; qt < 4; ++qt) {
      float4v am = __builtin_amdgcn_mfma_f32_16x16x32_f16(ah[qt][0], bh0, cvec, 0, 0, 0);
      am = __builtin_amdgcn_mfma_f32_16x16x32_f16(ah[qt][1], bh1, am, 0, 0, 0);
      float4v ax = __builtin_amdgcn_mfma_f32_16x16x32_f16(ah[qt][0], bl0, zvec, 0, 0, 0);
      ax = __builtin_amdgcn_mfma_f32_16x16x32_f16(ah[qt][1], bl1, ax, 0, 0, 0);
      ax = __builtin_amdgcn_mfma_f32_16x16x32_f16(al[qt][0], bh0, ax, 0, 0, 0);
      ax = __builtin_amdgcn_mfma_f32_16x16x32_f16(al[qt][1], bh1, ax, 0, 0, 0);
#pragma unroll
      for (int r = 0; r < 4; ++r) {
        const float v = fmaf(4.8828125e-4f, ax[r], am[r]);  // 2^-11
        // k ascending in t per lane: strict > keeps lowest-k maximum.
        if (v > best[qt][r]) { best[qt][r] = v; bestk[qt][r] = k16; }
      }
    }
  }

  // Cross-lane argmax over the 16 cols (m) in each quad; ties -> lower k.
#pragma unroll
  for (int qt = 0; qt < 4; ++qt)
#pragma unroll
    for (int r = 0; r < 4; ++r) {
      float b = best[qt][r];
      int bk = bestk[qt][r];
#pragma unroll
      for (int s = 1; s < 16; s <<= 1) {
        const float ob = __shfl_xor(b, s);
        const int obk = __shfl_xor(bk, s);
        if (ob > b || (ob == b && obk < bk)) { b = ob; bk = obk; }
      }
      if (m == 0) {
        const int qb = qt * 16 + quad * 4 + r;  // C row = quad*4 + r
        rv[kh][qb] = b;
        rk[kh][qb] = bk;
      }
    }
  __syncthreads();

  // Combine the 4 K-quarters in order (strict >: ties -> lower kh = lower k).
  if (tid < 64) {
    float b = rv[0][tid];
    int bk = rk[0][tid];
#pragma unroll
    for (int h = 1; h < 4; ++h) {
      const float d = rv[h][tid];
      if (d > b) { b = d; bk = rk[h][tid]; }
    }
    sidx[tid] = bk;
  }
  __syncthreads();

  // Gather winning fp32 codebook rows; coalesced float4 writes.
  const size_t obase = (size_t)blockIdx.x * 64 * (DIM / 4);
#pragma unroll
  for (int f0 = 0; f0 < 64 * (DIM / 4); f0 += BLOCK) {
    const int f = f0 + tid;
    const int q = f >> 4, e = f & 15;
    out4[obase + f] = cb4[(size_t)sidx[q] * (DIM / 4) + e];
  }
}

extern "C" void kernel_launch(void* const* d_in, const int* in_sizes, int n_in,
                              void* d_out, int out_size, void* d_ws, size_t ws_size,
                              hipStream_t stream) {
  const float* z = (const float*)d_in[0];
  const float* cb = (const float*)d_in[1];
  char* ws = (char*)d_ws;
  float* csqn = (float*)(ws + WS_CSQN);
  _Float16* cbf = (_Float16*)(ws + WS_CBF);

  const int nq = in_sizes[0] / DIM;  // 65536
  prep_kernel<<<KCODES / 16, BLOCK, 0, stream>>>(cb, cbf, csqn);
  vq_mfma<<<nq / 64, BLOCK, 0, stream>>>(z, (const float4*)cb, cbf, csqn,
                                         (float4*)d_out);
}